// Round 15
// baseline (445.662 us; speedup 1.0000x reference)
//
#include <hip/hip_runtime.h>
#include <hip/hip_bf16.h>

// IRChannelAttention on MI355X. Round 15: 128-query attn supertiles (512 thr,
// 8 waves = 2 n-halves x 4 m-strips) -> K/V staging + barriers amortized over
// 2x FLOP. setup+pool fused (r13's benign part). 4 launches.
// B=2, C=64, H=W=80, N=6400. fp32 global I/O, bf16 ws intermediates.

#define BATCH 2
#define CH 64
#define HH 80
#define WW 80
#define NN 6400
#define NT 100          // 64-tiles (qkv)
#define NT2 50          // 128-supertiles (attn)
#define KS 10           // key splits
#define KTPS (NT/KS)    // 10 key tiles per split
#define EPSV 1e-5f
#define NEGBIG (-1e30f)
#define QP 72           // bf16 LDS tile pitch
#define LOG2E8 0.18033688f   // log2(e)/8, folded into Q weights
#define VSP 65          // qkv V-transpose LDS pitch

typedef __hip_bfloat16 bf16;
typedef __attribute__((ext_vector_type(8))) short short8;   // MFMA A/B frag
typedef __attribute__((ext_vector_type(4))) float f4;       // MFMA C/D frag
#define MFMA16 __builtin_amdgcn_mfma_f32_16x16x32_bf16

__device__ __forceinline__ float b2f(bf16 v){ return __bfloat162float(v); }
__device__ __forceinline__ bf16 f2b(float v){ return __float2bfloat16(v); }
__device__ __forceinline__ ushort f2bu(float v){ return ((__hip_bfloat16_raw)__float2bfloat16(v)).x; }
__device__ __forceinline__ float bu2f(ushort u){
  union { unsigned int i; float f; } w; w.i = ((unsigned int)u) << 16; return w.f;
}
__device__ __forceinline__ unsigned pkbf(float a, float b){
  union { __hip_bfloat162 h2; unsigned u; } cv;
  cv.h2 = __float22bfloat162_rn(make_float2(a, b));
  return cv.u;
}
__device__ __forceinline__ float fexp2(float x){
#if __has_builtin(__builtin_amdgcn_exp2f)
  return __builtin_amdgcn_exp2f(x);
#else
  return exp2f(x);
#endif
}

// ws layout (bytes)
#define OFF_BIAS 0                              // 192 fp32: BQ(scaled) BK BVP
#define OFF_WH_B 768                            // 4 x 4096 bf16: wq | wvp | wa1 | wa2m
#define OFF_LOW_B (768 + 32768)                 // lowg bf16 [b][c][n]
#define OFF_Q_B   (OFF_LOW_B + BATCH*CH*NN*2)   // qgT bf16 [b][n][c]
#define OFF_K_B   (OFF_Q_B   + BATCH*CH*NN*2)   // kgT bf16 [b][n][c]
#define OFF_V_B   (OFF_K_B   + BATCH*CH*NN*2)   // vgc (=V') bf16 [b][c][n]
#define OFF_P_B   (OFF_V_B   + BATCH*CH*NN*2)   // part bf16 [(b*NT2+st)*KS+s][64c][128n]
#define OFF_ML_B  (OFF_P_B   + BATCH*NT2*KS*8192*2) // l fp32 [(b*NT2+st)*KS+s][128]
// total ~23.5 MB

// ---------------------------------------------------------------------------
// setup_pool: blk 0..15 = weight fold (global-direct; co wave-uniform ->
// broadcast, ci lane-fast -> coalesced; L2-hot). blk 16..815 = maxpool low.
// ---------------------------------------------------------------------------
__global__ __launch_bounds__(256) void setup_pool(
    const float* __restrict__ x,
    const float* __restrict__ q1w, const float* __restrict__ q1g, const float* __restrict__ q1b,
    const float* __restrict__ q2w, const float* __restrict__ q2g, const float* __restrict__ q2b,
    const float* __restrict__ q3w, const float* __restrict__ q3g, const float* __restrict__ q3b,
    const float* __restrict__ khw, const float* __restrict__ khb,
    const float* __restrict__ klw, const float* __restrict__ klb,
    const float* __restrict__ kfw, const float* __restrict__ kfb,
    const float* __restrict__ vg,  const float* __restrict__ vbnb,
    const float* __restrict__ vw,  const float* __restrict__ vb,
    const float* __restrict__ outw,
    float* __restrict__ biasf, bf16* __restrict__ wh, bf16* __restrict__ lowg)
{
  __shared__ float sbv[64];
  int tid = threadIdx.x;
  int blk = blockIdx.x;

  if (blk < 16) {
    float rs = rsqrtf(1.0f + EPSV);
    bf16* wq   = wh;
    bf16* wvp  = wh + 4096;
    bf16* wa1  = wh + 8192;
    bf16* wa2m = wh + 12288;

    int t = blk*256 + tid;
    int ci = t & 63, co = t >> 6;
    int o = ci*64 + co;

    float w = 0.f, g;
    if (co < 21)      { g = q1g[co];    w = (ci < 21)              ? q1w[co*21 + ci]            : 0.f; }
    else if (co < 42) { g = q2g[co-21]; w = (ci >= 21 && ci < 42)  ? q2w[(co-21)*21 + (ci-21)]  : 0.f; }
    else              { g = q3g[co-42]; w = (ci >= 42)             ? q3w[(co-42)*22 + (ci-42)]  : 0.f; }
    wq[o] = f2b(w * g * rs * LOG2E8);

    float a1 = 0.f, a2 = 0.f, av = 0.f;
    #pragma unroll 8
    for (int j = 0; j < 32; ++j) {
      a1 += kfw[co*64 + j]      * khw[j*64 + ci];
      a2 += kfw[co*64 + 32 + j] * klw[j*64 + ci];
    }
    #pragma unroll 8
    for (int j = 0; j < 64; ++j)
      av += outw[co*64 + j] * vw[j*64 + ci];
    wa1[o]  = f2b(a1);
    wa2m[o] = f2b(a2 - a1);              // K = A1@x + (A2-A1)@low + bK
    wvp[o]  = f2b(av * vg[ci] * rs);     // V' = Wo @ Wv_bn

    if (blk == 0) {
      if (tid < 64) {
        int j = tid;
        float bvo = vb[j];
        for (int c2 = 0; c2 < 64; ++c2) bvo += vw[j*64 + c2] * vbnb[c2];
        sbv[j] = bvo;
      }
      __syncthreads();
      if (tid < 64) {
        int c2 = tid;
        float bq;
        if (c2 < 21)      bq = q1b[c2];
        else if (c2 < 42) bq = q2b[c2-21];
        else              bq = q3b[c2-42];
        biasf[c2] = bq * LOG2E8;
        float bk = kfb[c2];
        #pragma unroll 8
        for (int j = 0; j < 32; ++j) {
          bk += kfw[c2*64 + j]      * khb[j];
          bk += kfw[c2*64 + 32 + j] * klb[j];
        }
        biasf[64 + c2] = bk;
        float bvp = 0.f;
        #pragma unroll 8
        for (int j = 0; j < 64; ++j) bvp += outw[c2*64 + j] * sbv[j];
        biasf[128 + c2] = bvp;
      }
    }
  } else {
    // ---- pool: 4 outputs/thread ----
    int t4 = ((blk - 16)*256 + tid)*4;
    int bc = t4 / NN; int n = t4 % NN;
    int h = n / WW, w0 = n % WW;
    const float* p = x + bc*NN;
    float m5[4], m3[4];
    #pragma unroll
    for (int j=0;j<4;++j){ m5[j]=NEGBIG; m3[j]=NEGBIG; }
    #pragma unroll
    for (int dh = -2; dh <= 2; ++dh) {
      int hh = h + dh; if (hh < 0 || hh >= HH) continue;
      float r[12];
      const float* row = p + hh*WW;
      if (w0 >= 4)      { float4 a = *(const float4*)&row[w0-4]; r[0]=a.x;r[1]=a.y;r[2]=a.z;r[3]=a.w; }
      else              { r[0]=NEGBIG;r[1]=NEGBIG;r[2]=NEGBIG;r[3]=NEGBIG; }
      { float4 a = *(const float4*)&row[w0]; r[4]=a.x;r[5]=a.y;r[6]=a.z;r[7]=a.w; }
      if (w0 + 7 < WW)  { float4 a = *(const float4*)&row[w0+4]; r[8]=a.x;r[9]=a.y;r[10]=a.z;r[11]=a.w; }
      else              { r[8]=NEGBIG;r[9]=NEGBIG;r[10]=NEGBIG;r[11]=NEGBIG; }
      bool in3 = (dh >= -1 && dh <= 1);
      #pragma unroll
      for (int j=0;j<4;++j) {
        float v3 = fmaxf(fmaxf(r[3+j], r[4+j]), r[5+j]);
        float v5 = fmaxf(fmaxf(r[2+j], v3), r[6+j]);
        m5[j] = fmaxf(m5[j], v5);
        if (in3) m3[j] = fmaxf(m3[j], v3);
      }
    }
    ushort4 o;
    o.x = f2bu(0.5f*(m3[0]+m5[0]));
    o.y = f2bu(0.5f*(m3[1]+m5[1]));
    o.z = f2bu(0.5f*(m3[2]+m5[2]));
    o.w = f2bu(0.5f*(m3[3]+m5[3]));
    *(ushort4*)&lowg[t4] = o;
  }
}

// ---------------------------------------------------------------------------
// qkv_kernel: unchanged (r12 best variant). Q,K [b][n][c]; V' [b][c][n].
// ---------------------------------------------------------------------------
__global__ __launch_bounds__(256) void qkv_kernel(
    const float* __restrict__ x, const float* __restrict__ biasf,
    const bf16* __restrict__ wh, const bf16* __restrict__ lowg,
    bf16* __restrict__ qgT, bf16* __restrict__ kgT, bf16* __restrict__ vgc)
{
  __shared__ __align__(16) float xs[64*32];
  __shared__ __align__(16) float lows[64*32];
  __shared__ __align__(16) bf16  wbuf[16384];
  __shared__ ushort vs[64*VSP];
  __shared__ float bias[192];

  int tid = threadIdx.x;
  int blk = blockIdx.x;
  int b = blk / (NT*2);
  int rem = blk % (NT*2);
  int tile = rem >> 1, half = rem & 1;
  int n0 = tile*64 + half*32;

  #pragma unroll
  for (int i = 0; i < 8; ++i) {
    int e = i*256 + tid; int c = e >> 5, p = e & 31;
    xs[c*32 + p]   = x[(b*CH + c)*NN + n0 + p];
    lows[c*32 + p] = b2f(lowg[(b*CH + c)*NN + n0 + p]);
  }
  #pragma unroll
  for (int i = 0; i < 16; ++i)
    ((uint2*)wbuf)[i*256 + tid] = ((const uint2*)wh)[i*256 + tid];
  if (tid < 192) bias[tid] = biasf[tid];
  __syncthreads();

  int co = tid & 63, pg = tid >> 6;
  const bf16* wq   = wbuf;
  const bf16* wvp  = wbuf + 4096;
  const bf16* wa1  = wbuf + 8192;
  const bf16* wa2m = wbuf + 12288;

  // ---- Q ----
  {
    float bq = bias[co];
    float4 a0 = make_float4(bq,bq,bq,bq), a1v = a0;
    for (int ci = 0; ci < 64; ++ci) {
      float wv = b2f(wq[ci*64 + co]);
      float4 x0 = *(const float4*)&xs[ci*32 + pg*8];
      float4 x1 = *(const float4*)&xs[ci*32 + pg*8 + 4];
      a0.x += wv*x0.x; a0.y += wv*x0.y; a0.z += wv*x0.z; a0.w += wv*x0.w;
      a1v.x += wv*x1.x; a1v.y += wv*x1.y; a1v.z += wv*x1.z; a1v.w += wv*x1.w;
    }
    float q8[8] = {a0.x,a0.y,a0.z,a0.w,a1v.x,a1v.y,a1v.z,a1v.w};
    #pragma unroll
    for (int j=0;j<8;++j)
      qgT[(size_t)(b*NN + n0 + pg*8 + j)*64 + co] = f2b(fmaxf(q8[j], 0.f));
  }
  // ---- V' ----
  {
    float bv = bias[128 + co];
    float4 a0 = make_float4(bv,bv,bv,bv), a1v = a0;
    for (int ci = 0; ci < 64; ++ci) {
      float wv = b2f(wvp[ci*64 + co]);
      float4 x0 = *(const float4*)&xs[ci*32 + pg*8];
      float4 x1 = *(const float4*)&xs[ci*32 + pg*8 + 4];
      a0.x += wv*x0.x; a0.y += wv*x0.y; a0.z += wv*x0.z; a0.w += wv*x0.w;
      a1v.x += wv*x1.x; a1v.y += wv*x1.y; a1v.z += wv*x1.z; a1v.w += wv*x1.w;
    }
    float v8[8] = {a0.x,a0.y,a0.z,a0.w,a1v.x,a1v.y,a1v.z,a1v.w};
    #pragma unroll
    for (int j=0;j<8;++j)
      vs[co*VSP + pg*8 + j] = f2bu(v8[j]);
  }
  __syncthreads();
  {
    int c = tid >> 2, cb = (tid & 3)*8;
    ushort u[8];
    #pragma unroll
    for (int j=0;j<8;++j) u[j] = vs[c*VSP + cb + j];
    uint4 pk;
    pk.x = (uint)u[0] | ((uint)u[1] << 16);
    pk.y = (uint)u[2] | ((uint)u[3] << 16);
    pk.z = (uint)u[4] | ((uint)u[5] << 16);
    pk.w = (uint)u[6] | ((uint)u[7] << 16);
    *(uint4*)&vgc[(size_t)(b*CH + c)*NN + n0 + cb] = pk;
  }
  // ---- K ----
  {
    float bk = bias[64 + co];
    float4 a0 = make_float4(bk,bk,bk,bk), a1v = a0;
    for (int ci = 0; ci < 64; ++ci) {
      float w1 = b2f(wa1[ci*64 + co]);
      float w2 = b2f(wa2m[ci*64 + co]);
      float4 x0 = *(const float4*)&xs[ci*32 + pg*8];
      float4 x1 = *(const float4*)&xs[ci*32 + pg*8 + 4];
      float4 l0 = *(const float4*)&lows[ci*32 + pg*8];
      float4 l1 = *(const float4*)&lows[ci*32 + pg*8 + 4];
      a0.x += w1*x0.x + w2*l0.x; a0.y += w1*x0.y + w2*l0.y;
      a0.z += w1*x0.z + w2*l0.z; a0.w += w1*x0.w + w2*l0.w;
      a1v.x += w1*x1.x + w2*l1.x; a1v.y += w1*x1.y + w2*l1.y;
      a1v.z += w1*x1.z + w2*l1.z; a1v.w += w1*x1.w + w2*l1.w;
    }
    float k8[8] = {a0.x,a0.y,a0.z,a0.w,a1v.x,a1v.y,a1v.z,a1v.w};
    #pragma unroll
    for (int j=0;j<8;++j)
      kgT[(size_t)(b*NN + n0 + pg*8 + j)*64 + co] = f2b(k8[j]);
  }
}

// ---------------------------------------------------------------------------
// attn_partial: 128-query supertile, 512 threads = 8 waves.
// wave wv: nh = wv>>2 (n-half), ms = wv&3 (m-strip).
// S^T = K.Q^T: A = K rows of m-strip ms, B = Q frags of n-half nh (hoisted).
// P [128n][64m] aliases Q region. PV: A = P rows of n-strip wv, B = V'.
// K/V staged once per iter serve 2x FLOP vs 64-query tiles.
// ---------------------------------------------------------------------------
__global__ __launch_bounds__(512, 8) void attn_partial(
    const bf16* __restrict__ qgT, const bf16* __restrict__ kgT, const bf16* __restrict__ vgc,
    ushort* __restrict__ part, float* __restrict__ pml)
{
  __shared__ __align__(16) char smem[36864];
  __shared__ float lred[512];
  bf16* Qld = (bf16*)smem;              // [128][QP] (dead after hoist)
  bf16* Pld = (bf16*)smem;              // aliases Qld: [128n][64m]
  bf16* Kld = (bf16*)(smem + 18432);    // [64][QP] m rows
  bf16* Vld = (bf16*)(smem + 27648);    // [64][QP] c rows

  int tid = threadIdx.x;
  int blk = blockIdx.x;
  int b = blk / (NT2*KS);
  int rem = blk % (NT2*KS);
  int st = rem / KS, split = rem % KS;
  int n0 = st*128;
  int wv = tid >> 6, lane = tid & 63, ln = lane & 15, quad = lane >> 4;
  int nh = wv >> 2, ms = wv & 3;
  int arowK = (ms*16 + ln)*QP;
  int arowP = (wv*16 + ln)*QP;

  // stage Q [128n][c]; hoist this wave's n-half as B-frags
  #pragma unroll
  for (int i = 0; i < 4; ++i) {
    int f = (i*512 + tid)*4; int n = f >> 6, c = f & 63;
    *(uint2*)&Qld[n*QP + c] = *(const uint2*)&qgT[(size_t)(b*NN + n0 + n)*64 + c];
  }
  __syncthreads();
  short8 bq[4][2];
  #pragma unroll
  for (int nt = 0; nt < 4; ++nt) {
    bq[nt][0] = *(const short8*)&Qld[(nh*64 + nt*16 + ln)*QP + quad*8];
    bq[nt][1] = *(const short8*)&Qld[(nh*64 + nt*16 + ln)*QP + 32 + quad*8];
  }

  f4 accO[4];
  float lacc[4];
  #pragma unroll
  for (int t=0;t<4;++t) accO[t] = (f4){0.f,0.f,0.f,0.f};
  #pragma unroll
  for (int nt=0;nt<4;++nt) lacc[nt] = 0.f;

  // prefetch tile 0
  uint2 kreg[2], vreg[2];
  int mbase = split*KTPS*64;
  #pragma unroll
  for (int i = 0; i < 2; ++i) {
    int f = (i*512 + tid)*4; int rr = f >> 6, cc = f & 63;
    kreg[i] = *(const uint2*)&kgT[(size_t)(b*NN + mbase + rr)*64 + cc];
    vreg[i] = *(const uint2*)&vgc[(size_t)(b*CH + rr)*NN + mbase + cc];
  }

  for (int kt = 0; kt < KTPS; ++kt) {
    __syncthreads();   // bar1: prior PV frag reads done
    #pragma unroll
    for (int i = 0; i < 2; ++i) {
      int f = (i*512 + tid)*4; int rr = f >> 6, cc = f & 63;
      *(uint2*)&Kld[rr*QP + cc] = kreg[i];
      *(uint2*)&Vld[rr*QP + cc] = vreg[i];
    }
    __syncthreads();   // bar2: staging visible
    if (kt + 1 < KTPS) {
      int m0 = mbase + (kt+1)*64;
      #pragma unroll
      for (int i = 0; i < 2; ++i) {
        int f = (i*512 + tid)*4; int rr = f >> 6, cc = f & 63;
        kreg[i] = *(const uint2*)&kgT[(size_t)(b*NN + m0 + rr)*64 + cc];
        vreg[i] = *(const uint2*)&vgc[(size_t)(b*CH + rr)*NN + m0 + cc];
      }
    }

    // ---- S^T = K Q^T for (m-strip ms) x (n-half nh) ----
    short8 ak0 = *(const short8*)&Kld[arowK + quad*8];
    short8 ak1 = *(const short8*)&Kld[arowK + 32 + quad*8];
    f4 accS[4];
    #pragma unroll
    for (int nt = 0; nt < 4; ++nt) {
      f4 z = (f4){0.f,0.f,0.f,0.f};
      z = MFMA16(ak0, bq[nt][0], z, 0, 0, 0);
      accS[nt] = MFMA16(ak1, bq[nt][1], z, 0, 0, 0);
    }
    // ---- P = exp2(S): lane holds m = ms*16+quad*4+r, n = nh*64+nt*16+ln ----
    #pragma unroll
    for (int nt = 0; nt < 4; ++nt) {
      float p0 = fexp2(accS[nt][0]), p1 = fexp2(accS[nt][1]);
      float p2 = fexp2(accS[nt][2]), p3 = fexp2(accS[nt][3]);
      lacc[nt] += (p0 + p1) + (p2 + p3);
      uint2 pk;
      pk.x = pkbf(p0, p1);
      pk.y = pkbf(p2, p3);
      *(uint2*)&Pld[(nh*64 + nt*16 + ln)*QP + ms*16 + quad*4] = pk;
    }
    __syncthreads();   // bar3: P visible

    // ---- O += P V'^T: A = P rows of n-strip wv, B = V' ----
    short8 ap0 = *(const short8*)&Pld[arowP + quad*8];
    short8 ap1 = *(const short8*)&Pld[arowP + 32 + quad*8];
    #pragma unroll
    for (int t = 0; t < 4; ++t) {
      short8 bv0 = *(const short8*)&Vld[(t*16+ln)*QP + quad*8];
      short8 bv1 = *(const short8*)&Vld[(t*16+ln)*QP + 32 + quad*8];
      accO[t] = MFMA16(ap0, bv0, accO[t], 0, 0, 0);
      accO[t] = MFMA16(ap1, bv1, accO[t], 0, 0, 0);
    }
  }

  // ---- store partials bf16 [64c][128n]: O[n = wv*16+quad*4+r][c = t*16+ln] ----
  size_t pbase = ((size_t)(b*NT2 + st)*KS + split)*8192;
  ushort* pp = part + pbase;
  #pragma unroll
  for (int t = 0; t < 4; ++t) {
    uint2 pk;
    pk.x = pkbf(accO[t][0], accO[t][1]);
    pk.y = pkbf(accO[t][2], accO[t][3]);
    *(uint2*)&pp[(size_t)(t*16 + ln)*128 + wv*16 + quad*4] = pk;
  }
  // ---- l: sum over m. lacc covers lane's 4 m; xor16/32 sums quads (m within
  // strip); cross-strip (waves ms=0..3 of same nh) summed via LDS. ----
  #pragma unroll
  for (int nt = 0; nt < 4; ++nt) {
    float s = lacc[nt];
    s += __shfl_xor(s, 16);
    s += __shfl_xor(s, 32);
    if (quad == 0) lred[wv*64 + nt*16 + ln] = s;
  }
  __syncthreads();
  if (tid < 128) {
    int nh2 = tid >> 6, j = tid & 63;
    float l = (lred[(nh2*4+0)*64 + j] + lred[(nh2*4+1)*64 + j])
            + (lred[(nh2*4+2)*64 + j] + lred[(nh2*4+3)*64 + j]);
    size_t mlb = ((size_t)(b*NT2 + st)*KS + split)*128;
    pml[mlb + tid] = l;
  }
}

// ---------------------------------------------------------------------------
// attn_reduce: streaming. One block per (b, supertile, c-half of 32).
// out[c][n] = sum_s part[s][c][n]/l[n] + outb[c] + x[c][n].
// ---------------------------------------------------------------------------
__global__ __launch_bounds__(256) void attn_reduce(
    const ushort* __restrict__ part, const float* __restrict__ pml,
    const float* __restrict__ x, const float* __restrict__ outb,
    float* __restrict__ out)
{
  __shared__ float linv[128];
  __shared__ float ob[64];

  int tid = threadIdx.x;
  int blk = blockIdx.x;
  int b = blk / (NT2*2);
  int rem = blk % (NT2*2);
  int st = rem >> 1, half = rem & 1;
  size_t base = (size_t)(b*NT2 + st)*KS;

  if (tid < 128) {
    float l = 0.f;
    #pragma unroll
    for (int s=0;s<KS;++s) l += pml[(base+s)*128 + tid];
    linv[tid] = 1.0f / l;
  }
  if (tid >= 128 && tid < 192) ob[tid-128] = outb[tid-128];
  __syncthreads();

  // this block: c in [half*32, half*32+32). 32c x 128n = 1024 uint2-chunks.
  #pragma unroll
  for (int j = 0; j < 4; ++j) {
    int idx = j*256 + tid;
    int c = half*32 + (idx >> 5), q = idx & 31;
    float a0=0.f, a1=0.f, a2=0.f, a3=0.f;
    #pragma unroll
    for (int s = 0; s < KS; ++s) {
      uint2 v = *(const uint2*)&part[(base+s)*8192 + (size_t)c*128 + q*4];
      a0 += bu2f((ushort)(v.x & 0xffff)); a1 += bu2f((ushort)(v.x >> 16));
      a2 += bu2f((ushort)(v.y & 0xffff)); a3 += bu2f((ushort)(v.y >> 16));
    }
    int nl = q*4;
    size_t gidx = (size_t)(b*CH + c)*NN + st*128 + nl;
    float4 xv = *(const float4*)&x[gidx];
    float bc = ob[c];
    float4 o;
    o.x = a0*linv[nl+0] + bc + xv.x;
    o.y = a1*linv[nl+1] + bc + xv.y;
    o.z = a2*linv[nl+2] + bc + xv.z;
    o.w = a3*linv[nl+3] + bc + xv.w;
    *(float4*)&out[gidx] = o;
  }
}

extern "C" void kernel_launch(void* const* d_in, const int* in_sizes, int n_in,
                              void* d_out, int out_size, void* d_ws, size_t ws_size,
                              hipStream_t stream) {
  const float* x    = (const float*)d_in[0];
  const float* q1w  = (const float*)d_in[1];
  const float* q1g  = (const float*)d_in[2];
  const float* q1b  = (const float*)d_in[3];
  const float* q2w  = (const float*)d_in[4];
  const float* q2g  = (const float*)d_in[5];
  const float* q2b  = (const float*)d_in[6];
  const float* q3w  = (const float*)d_in[7];
  const float* q3g  = (const float*)d_in[8];
  const float* q3b  = (const float*)d_in[9];
  const float* khw  = (const float*)d_in[10];
  const float* khb  = (const float*)d_in[11];
  const float* klw  = (const float*)d_in[12];
  const float* klb  = (const float*)d_in[13];
  const float* kfw  = (const float*)d_in[14];
  const float* kfb  = (const float*)d_in[15];
  const float* vbg  = (const float*)d_in[16];
  const float* vbb  = (const float*)d_in[17];
  const float* vw   = (const float*)d_in[18];
  const float* vb   = (const float*)d_in[19];
  const float* outw = (const float*)d_in[20];
  const float* outb = (const float*)d_in[21];

  char*   wsb  = (char*)d_ws;
  float*  biasf= (float*)(wsb + OFF_BIAS);
  bf16*   wh   = (bf16*)(wsb + OFF_WH_B);
  bf16*   lowg = (bf16*)(wsb + OFF_LOW_B);
  bf16*   qgT  = (bf16*)(wsb + OFF_Q_B);
  bf16*   kgT  = (bf16*)(wsb + OFF_K_B);
  bf16*   vgc  = (bf16*)(wsb + OFF_V_B);
  ushort* part = (ushort*)(wsb + OFF_P_B);
  float*  pml  = (float*)(wsb + OFF_ML_B);

  hipLaunchKernelGGL(setup_pool, dim3(16 + BATCH*CH*NN/1024), dim3(256), 0, stream,
                     x, q1w,q1g,q1b,q2w,q2g,q2b,q3w,q3g,q3b,
                     khw,khb,klw,klb,kfw,kfb,vbg,vbb,vw,vb,outw,
                     biasf, wh, lowg);
  hipLaunchKernelGGL(qkv_kernel, dim3(BATCH*NT*2), dim3(256), 0, stream,
                     x, biasf, wh, lowg, qgT, kgT, vgc);
  hipLaunchKernelGGL(attn_partial, dim3(BATCH*NT2*KS), dim3(512), 0, stream,
                     qgT, kgT, vgc, part, pml);
  hipLaunchKernelGGL(attn_reduce, dim3(BATCH*NT2*2), dim3(256), 0, stream,
                     part, pml, x, outb, (float*)d_out);
}

// Round 16
// 169.317 us; speedup vs baseline: 2.6321x; 2.6321x over previous
//
#include <hip/hip_runtime.h>
#include <hip/hip_bf16.h>

// IRChannelAttention on MI355X. Round 16: RESTORE best-measured config
// (r12 pipeline, 171.2us): setup_fold(16) -> pool_low(800) -> qkv(400) ->
// attn_partial(2000, plain bounds, 72 VGPR) -> attn_reduce(200, streaming).
// r15's forced-occupancy spill (32 VGPR, 630MB scratch writes) reverted.
// B=2, C=64, H=W=80, N=6400. fp32 global I/O, bf16 ws intermediates.

#define BATCH 2
#define CH 64
#define HH 80
#define WW 80
#define NN 6400
#define NT 100          // NN / 64
#define KS 10           // key splits (divides NT)
#define KTPS (NT/KS)    // 10 key tiles per split
#define EPSV 1e-5f
#define NEGBIG (-1e30f)
#define QP 72           // bf16 LDS tile pitch
#define LOG2E8 0.18033688f   // log2(e)/8, folded into Q weights
#define VSP 65          // qkv V-transpose LDS pitch (odd -> 2-way banks, free)

typedef __hip_bfloat16 bf16;
typedef __attribute__((ext_vector_type(8))) short short8;   // MFMA A/B frag
typedef __attribute__((ext_vector_type(4))) float f4;       // MFMA C/D frag
#define MFMA16 __builtin_amdgcn_mfma_f32_16x16x32_bf16

__device__ __forceinline__ float b2f(bf16 v){ return __bfloat162float(v); }
__device__ __forceinline__ bf16 f2b(float v){ return __float2bfloat16(v); }
__device__ __forceinline__ ushort f2bu(float v){ return ((__hip_bfloat16_raw)__float2bfloat16(v)).x; }
__device__ __forceinline__ float bu2f(ushort u){
  union { unsigned int i; float f; } w; w.i = ((unsigned int)u) << 16; return w.f;
}
__device__ __forceinline__ unsigned pkbf(float a, float b){   // packed bf16x2
  union { __hip_bfloat162 h2; unsigned u; } cv;
  cv.h2 = __float22bfloat162_rn(make_float2(a, b));
  return cv.u;
}
__device__ __forceinline__ float fexp2(float x){
#if __has_builtin(__builtin_amdgcn_exp2f)
  return __builtin_amdgcn_exp2f(x);
#else
  return exp2f(x);
#endif
}

// ws layout (bytes)
#define OFF_BIAS 0                              // 192 fp32: BQ(scaled) BK BVP
#define OFF_WH_B 768                            // 4 x 4096 bf16: wq | wvp | wa1 | wa2m
#define OFF_LOW_B (768 + 32768)                 // lowg bf16 [b][c][n]
#define OFF_Q_B   (OFF_LOW_B + BATCH*CH*NN*2)   // qgT bf16 [b][n][c]
#define OFF_K_B   (OFF_Q_B   + BATCH*CH*NN*2)   // kgT bf16 [b][n][c]
#define OFF_V_B   (OFF_K_B   + BATCH*CH*NN*2)   // vgc (=V') bf16 [b][c][n]
#define OFF_P_B   (OFF_V_B   + BATCH*CH*NN*2)   // part bf16 [(b*NT+t)*KS+s][c][n]
#define OFF_ML_B  (OFF_P_B   + BATCH*NT*KS*4096*2) // l fp32 [(b*NT+t)*KS+s][64]
// total ~23.5 MB

// grid 16 x 256: one (ci,co) per thread; lane -> ci (stride-1 LDS reads),
// co wave-uniform (broadcast). All chained weights staged to LDS per block.
// Folds: wq (+BN+softmax scale), wa1/wa2m (K chain), wvp = Wo @ (vw*bnscale).
__global__ __launch_bounds__(256) void setup_fold(
    const float* __restrict__ q1w, const float* __restrict__ q1g, const float* __restrict__ q1b,
    const float* __restrict__ q2w, const float* __restrict__ q2g, const float* __restrict__ q2b,
    const float* __restrict__ q3w, const float* __restrict__ q3g, const float* __restrict__ q3b,
    const float* __restrict__ khw, const float* __restrict__ khb,
    const float* __restrict__ klw, const float* __restrict__ klb,
    const float* __restrict__ kfw, const float* __restrict__ kfb,
    const float* __restrict__ vg,  const float* __restrict__ vbnb,
    const float* __restrict__ vw,  const float* __restrict__ vb,
    const float* __restrict__ outw,
    float* __restrict__ biasf, bf16* __restrict__ wh)
{
  __shared__ __align__(16) float skf[4096];   // kfw  [co][64]
  __shared__ __align__(16) float skh[2048];   // khw  [j][64ci]
  __shared__ __align__(16) float skl[2048];   // klw  [j][64ci]
  __shared__ __align__(16) float sow[4096];   // outw [co][64]
  __shared__ __align__(16) float svw[4096];   // vw   [j][64ci]
  __shared__ float sbv[64];                   // bv_old[j] = vb + vw@vbnb

  int tid = threadIdx.x;
  int blk = blockIdx.x;
  #pragma unroll
  for (int i = 0; i < 4; ++i) {
    *(float4*)&skf[(i*256 + tid)*4] = *(const float4*)&kfw[(i*256 + tid)*4];
    *(float4*)&sow[(i*256 + tid)*4] = *(const float4*)&outw[(i*256 + tid)*4];
    *(float4*)&svw[(i*256 + tid)*4] = *(const float4*)&vw[(i*256 + tid)*4];
  }
  #pragma unroll
  for (int i = 0; i < 2; ++i) {
    *(float4*)&skh[(i*256 + tid)*4] = *(const float4*)&khw[(i*256 + tid)*4];
    *(float4*)&skl[(i*256 + tid)*4] = *(const float4*)&klw[(i*256 + tid)*4];
  }
  __syncthreads();

  float rs = rsqrtf(1.0f + EPSV);
  // bv_old[j]: written and later read by the same wave (tid<64) -> wave-local
  // LDS ordering suffices, no extra barrier needed.
  if (tid < 64) {
    int j = tid;
    float bvo = vb[j];
    for (int ci2 = 0; ci2 < 64; ++ci2) bvo += svw[j*64 + ci2] * vbnb[ci2];
    sbv[j] = bvo;
  }

  bf16* wq   = wh;
  bf16* wvp  = wh + 4096;
  bf16* wa1  = wh + 8192;
  bf16* wa2m = wh + 12288;

  int t = blk*256 + tid;
  int ci = t & 63, co = t >> 6;        // ci = lane-fast
  int o = ci*64 + co;                  // transposed [ci][co] storage index

  float w = 0.f, g;
  if (co < 21)      { g = q1g[co];    w = (ci < 21)              ? q1w[co*21 + ci]            : 0.f; }
  else if (co < 42) { g = q2g[co-21]; w = (ci >= 21 && ci < 42)  ? q2w[(co-21)*21 + (ci-21)]  : 0.f; }
  else              { g = q3g[co-42]; w = (ci >= 42)             ? q3w[(co-42)*22 + (ci-42)]  : 0.f; }
  wq[o] = f2b(w * g * rs * LOG2E8);

  float a1 = 0.f, a2 = 0.f;
  #pragma unroll
  for (int j = 0; j < 32; ++j) {
    a1 += skf[co*64 + j]      * skh[j*64 + ci];
    a2 += skf[co*64 + 32 + j] * skl[j*64 + ci];
  }
  wa1[o]  = f2b(a1);
  wa2m[o] = f2b(a2 - a1);              // K = A1@x + (A2-A1)@low + bK

  // V' weight: wvp[ci][co] = rs*vg[ci] * sum_j outw[co][j]*vw[j][ci]
  float av = 0.f;
  #pragma unroll
  for (int j = 0; j < 64; ++j)
    av += sow[co*64 + j] * svw[j*64 + ci];
  wvp[o] = f2b(av * vg[ci] * rs);

  if (blk == 0 && tid < 64) {
    int c2 = tid;
    float bq;
    if (c2 < 21)      bq = q1b[c2];
    else if (c2 < 42) bq = q2b[c2-21];
    else              bq = q3b[c2-42];
    biasf[c2] = bq * LOG2E8;
    float bk = kfb[c2];
    #pragma unroll
    for (int j = 0; j < 32; ++j) {
      bk += skf[c2*64 + j]      * khb[j];
      bk += skf[c2*64 + 32 + j] * klb[j];
    }
    biasf[64 + c2] = bk;
    // folded V' bias: bvp = Wo @ bv_old (sbv written by this same wave)
    float bvp = 0.f;
    #pragma unroll
    for (int j = 0; j < 64; ++j) bvp += sow[c2*64 + j] * sbv[j];
    biasf[128 + c2] = bvp;
  }
}

// 4 outputs/thread, aligned float4 sliding windows. grid 800.
__global__ __launch_bounds__(256) void pool_low(const float* __restrict__ x,
                                                bf16* __restrict__ lowg)
{
  int t4 = (blockIdx.x*256 + threadIdx.x)*4;
  int bc = t4 / NN; int n = t4 % NN;
  int h = n / WW, w0 = n % WW;                 // w0 multiple of 4
  const float* p = x + bc*NN;
  float m5[4], m3[4];
  #pragma unroll
  for (int j=0;j<4;++j){ m5[j]=NEGBIG; m3[j]=NEGBIG; }
  #pragma unroll
  for (int dh = -2; dh <= 2; ++dh) {
    int hh = h + dh; if (hh < 0 || hh >= HH) continue;
    float r[12];
    const float* row = p + hh*WW;
    if (w0 >= 4)      { float4 a = *(const float4*)&row[w0-4]; r[0]=a.x;r[1]=a.y;r[2]=a.z;r[3]=a.w; }
    else              { r[0]=NEGBIG;r[1]=NEGBIG;r[2]=NEGBIG;r[3]=NEGBIG; }
    { float4 a = *(const float4*)&row[w0]; r[4]=a.x;r[5]=a.y;r[6]=a.z;r[7]=a.w; }
    if (w0 + 7 < WW)  { float4 a = *(const float4*)&row[w0+4]; r[8]=a.x;r[9]=a.y;r[10]=a.z;r[11]=a.w; }
    else              { r[8]=NEGBIG;r[9]=NEGBIG;r[10]=NEGBIG;r[11]=NEGBIG; }
    bool in3 = (dh >= -1 && dh <= 1);
    #pragma unroll
    for (int j=0;j<4;++j) {
      float v3 = fmaxf(fmaxf(r[3+j], r[4+j]), r[5+j]);
      float v5 = fmaxf(fmaxf(r[2+j], v3), r[6+j]);
      m5[j] = fmaxf(m5[j], v5);
      if (in3) m3[j] = fmaxf(m3[j], v3);
    }
  }
  ushort4 o;
  o.x = f2bu(0.5f*(m3[0]+m5[0]));
  o.y = f2bu(0.5f*(m3[1]+m5[1]));
  o.z = f2bu(0.5f*(m3[2]+m5[2]));
  o.w = f2bu(0.5f*(m3[3]+m5[3]));
  *(ushort4*)&lowg[t4] = o;
}

// One block per (b, tile, half): 32 positions. Weights LDS-resident (bf16).
// Q,K stored [b][n][c] (coalesced); V' transposed via LDS -> [b][c][n].
__global__ __launch_bounds__(256) void qkv_kernel(
    const float* __restrict__ x, const float* __restrict__ biasf,
    const bf16* __restrict__ wh, const bf16* __restrict__ lowg,
    bf16* __restrict__ qgT, bf16* __restrict__ kgT, bf16* __restrict__ vgc)
{
  __shared__ __align__(16) float xs[64*32];
  __shared__ __align__(16) float lows[64*32];
  __shared__ __align__(16) bf16  wbuf[16384];   // wq | wvp | wa1 | wa2m
  __shared__ ushort vs[64*VSP];                 // V' transpose buffer [co][p]
  __shared__ float bias[192];

  int tid = threadIdx.x;
  int blk = blockIdx.x;
  int b = blk / (NT*2);
  int rem = blk % (NT*2);
  int tile = rem >> 1, half = rem & 1;
  int n0 = tile*64 + half*32;

  #pragma unroll
  for (int i = 0; i < 8; ++i) {
    int e = i*256 + tid; int c = e >> 5, p = e & 31;
    xs[c*32 + p]   = x[(b*CH + c)*NN + n0 + p];
    lows[c*32 + p] = b2f(lowg[(b*CH + c)*NN + n0 + p]);
  }
  #pragma unroll
  for (int i = 0; i < 16; ++i)
    ((uint2*)wbuf)[i*256 + tid] = ((const uint2*)wh)[i*256 + tid];
  if (tid < 192) bias[tid] = biasf[tid];
  __syncthreads();

  int co = tid & 63, pg = tid >> 6;   // 8 positions per thread
  const bf16* wq   = wbuf;
  const bf16* wvp  = wbuf + 4096;
  const bf16* wa1  = wbuf + 8192;
  const bf16* wa2m = wbuf + 12288;

  // ---- Q (scaled, ReLU) ----
  {
    float bq = bias[co];
    float4 a0 = make_float4(bq,bq,bq,bq), a1v = a0;
    for (int ci = 0; ci < 64; ++ci) {
      float wv = b2f(wq[ci*64 + co]);
      float4 x0 = *(const float4*)&xs[ci*32 + pg*8];
      float4 x1 = *(const float4*)&xs[ci*32 + pg*8 + 4];
      a0.x += wv*x0.x; a0.y += wv*x0.y; a0.z += wv*x0.z; a0.w += wv*x0.w;
      a1v.x += wv*x1.x; a1v.y += wv*x1.y; a1v.z += wv*x1.z; a1v.w += wv*x1.w;
    }
    float q8[8] = {a0.x,a0.y,a0.z,a0.w,a1v.x,a1v.y,a1v.z,a1v.w};
    #pragma unroll
    for (int j=0;j<8;++j)
      qgT[(size_t)(b*NN + n0 + pg*8 + j)*64 + co] = f2b(fmaxf(q8[j], 0.f));
  }
  // ---- V' = (Wo@Wv_bn)@x + folded bias (to LDS, then coalesced [c][n]) ----
  {
    float bv = bias[128 + co];
    float4 a0 = make_float4(bv,bv,bv,bv), a1v = a0;
    for (int ci = 0; ci < 64; ++ci) {
      float wv = b2f(wvp[ci*64 + co]);
      float4 x0 = *(const float4*)&xs[ci*32 + pg*8];
      float4 x1 = *(const float4*)&xs[ci*32 + pg*8 + 4];
      a0.x += wv*x0.x; a0.y += wv*x0.y; a0.z += wv*x0.z; a0.w += wv*x0.w;
      a1v.x += wv*x1.x; a1v.y += wv*x1.y; a1v.z += wv*x1.z; a1v.w += wv*x1.w;
    }
    float v8[8] = {a0.x,a0.y,a0.z,a0.w,a1v.x,a1v.y,a1v.z,a1v.w};
    #pragma unroll
    for (int j=0;j<8;++j)
      vs[co*VSP + pg*8 + j] = f2bu(v8[j]);
  }
  __syncthreads();
  {
    int c = tid >> 2, cb = (tid & 3)*8;      // channel c, 8 positions
    ushort u[8];
    #pragma unroll
    for (int j=0;j<8;++j) u[j] = vs[c*VSP + cb + j];
    uint4 pk;
    pk.x = (uint)u[0] | ((uint)u[1] << 16);
    pk.y = (uint)u[2] | ((uint)u[3] << 16);
    pk.z = (uint)u[4] | ((uint)u[5] << 16);
    pk.w = (uint)u[6] | ((uint)u[7] << 16);
    *(uint4*)&vgc[(size_t)(b*CH + c)*NN + n0 + cb] = pk;
  }
  // ---- K = A1@x + (A2-A1)@low + bK (one pass) ----
  {
    float bk = bias[64 + co];
    float4 a0 = make_float4(bk,bk,bk,bk), a1v = a0;
    for (int ci = 0; ci < 64; ++ci) {
      float w1 = b2f(wa1[ci*64 + co]);
      float w2 = b2f(wa2m[ci*64 + co]);
      float4 x0 = *(const float4*)&xs[ci*32 + pg*8];
      float4 x1 = *(const float4*)&xs[ci*32 + pg*8 + 4];
      float4 l0 = *(const float4*)&lows[ci*32 + pg*8];
      float4 l1 = *(const float4*)&lows[ci*32 + pg*8 + 4];
      a0.x += w1*x0.x + w2*l0.x; a0.y += w1*x0.y + w2*l0.y;
      a0.z += w1*x0.z + w2*l0.z; a0.w += w1*x0.w + w2*l0.w;
      a1v.x += w1*x1.x + w2*l1.x; a1v.y += w1*x1.y + w2*l1.y;
      a1v.z += w1*x1.z + w2*l1.z; a1v.w += w1*x1.w + w2*l1.w;
    }
    float k8[8] = {a0.x,a0.y,a0.z,a0.w,a1v.x,a1v.y,a1v.z,a1v.w};
    #pragma unroll
    for (int j=0;j<8;++j)
      kgT[(size_t)(b*NN + n0 + pg*8 + j)*64 + co] = f2b(k8[j]);
  }
}

// ---------------------------------------------------------------------------
// attn_partial: split-K flash. S^T = K.Q^T (A = K rows of wave's m-strip,
// B = Q fully hoisted). P written as conflict-free b64 (cvt_pk packs).
// Partials (= P.V'^T unnormalized) bf16 [c][n]; l fp32. KS=10 -> 2000 blocks.
// Plain launch bounds: measured 72 VGPR / 4 blocks/CU / 51.7us (r12 best).
// ---------------------------------------------------------------------------
__global__ __launch_bounds__(256) void attn_partial(
    const bf16* __restrict__ qgT, const bf16* __restrict__ kgT, const bf16* __restrict__ vgc,
    ushort* __restrict__ part, float* __restrict__ pml)
{
  __shared__ __align__(16) char smem[27648];
  __shared__ float lred[256];
  bf16* Qld = (bf16*)smem;              // [64][QP] n rows (dead after hoist)
  bf16* Pld = (bf16*)smem;              // aliases Qld: [n][m]
  bf16* Kld = (bf16*)(smem + 9216);     // [64][QP] m rows
  bf16* Vld = (bf16*)(smem + 18432);    // [64][QP] c rows

  int tid = threadIdx.x;
  int blk = blockIdx.x;
  int b = blk / (NT*KS);
  int rem = blk % (NT*KS);
  int tile = rem / KS, split = rem % KS;
  int n0 = tile*64;
  int wv = tid >> 6, lane = tid & 63, ln = lane & 15, quad = lane >> 4;
  int arow = (wv*16 + ln)*QP;

  // stage Q [n][c]; hoist ALL Q as B-frags (loop-invariant)
  #pragma unroll
  for (int i = 0; i < 4; ++i) {
    int f = (i*256 + tid)*4; int n = f >> 6, c = f & 63;
    *(uint2*)&Qld[n*QP + c] = *(const uint2*)&qgT[(size_t)(b*NN + n0 + n)*64 + c];
  }
  __syncthreads();
  short8 bq[4][2];
  #pragma unroll
  for (int nt = 0; nt < 4; ++nt) {
    bq[nt][0] = *(const short8*)&Qld[(nt*16 + ln)*QP + quad*8];
    bq[nt][1] = *(const short8*)&Qld[(nt*16 + ln)*QP + 32 + quad*8];
  }

  f4 accO[4];
  float lacc[4];
  #pragma unroll
  for (int t=0;t<4;++t) accO[t] = (f4){0.f,0.f,0.f,0.f};
  #pragma unroll
  for (int nt=0;nt<4;++nt) lacc[nt] = 0.f;

  // prefetch tile 0
  uint2 kreg[4], vreg[4];
  int mbase = split*KTPS*64;
  #pragma unroll
  for (int i = 0; i < 4; ++i) {
    int f = (i*256 + tid)*4; int rr = f >> 6, cc = f & 63;
    kreg[i] = *(const uint2*)&kgT[(size_t)(b*NN + mbase + rr)*64 + cc];
    vreg[i] = *(const uint2*)&vgc[(size_t)(b*CH + rr)*NN + mbase + cc];
  }

  for (int kt = 0; kt < KTPS; ++kt) {
    __syncthreads();   // bar1: prior PV frag reads done; staging safe
    #pragma unroll
    for (int i = 0; i < 4; ++i) {
      int f = (i*256 + tid)*4; int rr = f >> 6, cc = f & 63;
      *(uint2*)&Kld[rr*QP + cc] = kreg[i];
      *(uint2*)&Vld[rr*QP + cc] = vreg[i];
    }
    __syncthreads();   // bar2: staging visible
    if (kt + 1 < KTPS) {
      int m0 = mbase + (kt+1)*64;
      #pragma unroll
      for (int i = 0; i < 4; ++i) {
        int f = (i*256 + tid)*4; int rr = f >> 6, cc = f & 63;
        kreg[i] = *(const uint2*)&kgT[(size_t)(b*NN + m0 + rr)*64 + cc];
        vreg[i] = *(const uint2*)&vgc[(size_t)(b*CH + rr)*NN + m0 + cc];
      }
    }

    // ---- S^T = K Q^T: wave's m-strip only (A = K rows wv*16+ln) ----
    short8 ak0 = *(const short8*)&Kld[arow + quad*8];
    short8 ak1 = *(const short8*)&Kld[arow + 32 + quad*8];
    f4 accS[4];
    #pragma unroll
    for (int nt = 0; nt < 4; ++nt) {
      f4 z = (f4){0.f,0.f,0.f,0.f};
      z = MFMA16(ak0, bq[nt][0], z, 0, 0, 0);
      accS[nt] = MFMA16(ak1, bq[nt][1], z, 0, 0, 0);
    }
    // ---- P = exp2(S): lane holds m=wv*16+quad*4+r, n=nt*16+ln ----
    #pragma unroll
    for (int nt = 0; nt < 4; ++nt) {
      float p0 = fexp2(accS[nt][0]), p1 = fexp2(accS[nt][1]);
      float p2 = fexp2(accS[nt][2]), p3 = fexp2(accS[nt][3]);
      lacc[nt] += (p0 + p1) + (p2 + p3);
      uint2 pk;
      pk.x = pkbf(p0, p1);
      pk.y = pkbf(p2, p3);
      *(uint2*)&Pld[(nt*16 + ln)*QP + wv*16 + quad*4] = pk;
    }
    __syncthreads();   // bar3: P (written by all waves) visible

    // ---- O += P V'^T (A = P rows of wave's n-strip, B = V') ----
    short8 ap0 = *(const short8*)&Pld[arow + quad*8];
    short8 ap1 = *(const short8*)&Pld[arow + 32 + quad*8];
    #pragma unroll
    for (int t = 0; t < 4; ++t) {
      short8 bv0 = *(const short8*)&Vld[(t*16+ln)*QP + quad*8];
      short8 bv1 = *(const short8*)&Vld[(t*16+ln)*QP + 32 + quad*8];
      accO[t] = MFMA16(ap0, bv0, accO[t], 0, 0, 0);
      accO[t] = MFMA16(ap1, bv1, accO[t], 0, 0, 0);
    }
  }

  // ---- store partials bf16 [c][n] (4 consecutive n at fixed c -> uint2) ----
  size_t pbase = ((size_t)(b*NT + tile)*KS + split)*4096;
  ushort* pp = part + pbase;
  #pragma unroll
  for (int t = 0; t < 4; ++t) {
    uint2 pk;
    pk.x = pkbf(accO[t][0], accO[t][1]);
    pk.y = pkbf(accO[t][2], accO[t][3]);
    *(uint2*)&pp[(t*16 + ln)*64 + wv*16 + quad*4] = pk;
  }
  // ---- l: butterfly quads within wave, then cross-wave via LDS ----
  #pragma unroll
  for (int nt = 0; nt < 4; ++nt) {
    float s = lacc[nt];
    s += __shfl_xor(s, 16);
    s += __shfl_xor(s, 32);
    if (quad == 0) lred[wv*64 + nt*16 + ln] = s;
  }
  __syncthreads();
  if (tid < 64) {
    size_t mlb = ((size_t)(b*NT + tile)*KS + split)*64;
    pml[mlb + tid] = (lred[tid] + lred[64 + tid]) + (lred[128 + tid] + lred[192 + tid]);
  }
}

// ---------------------------------------------------------------------------
// attn_reduce: PURE STREAMING (out-conv already folded into V'):
// out[c][n] = sum_s part[s][c][n] / l[n] + outb[c] + x[c][n].
// One block per (b, tile); coalesced uint2 part reads, float4 x/out.
// ---------------------------------------------------------------------------
__global__ __launch_bounds__(256) void attn_reduce(
    const ushort* __restrict__ part, const float* __restrict__ pml,
    const float* __restrict__ x, const float* __restrict__ outb,
    float* __restrict__ out)
{
  __shared__ float linv[64];
  __shared__ float ob[64];

  int tid = threadIdx.x;
  int blk = blockIdx.x;
  int b = blk / NT, tile = blk % NT;
  size_t base = (size_t)(b*NT + tile)*KS;

  if (tid < 64) {
    float l = 0.f;
    #pragma unroll
    for (int s=0;s<KS;++s) l += pml[(base+s)*64 + tid];
    linv[tid] = 1.0f / l;
    ob[tid] = outb[tid];
  }
  __syncthreads();

  // 1024 uint2-chunks (4 n's at fixed c). Wave: q=tid&15 spans a full 128B
  // row, c=tid>>4 -> 4 contiguous rows -> 512B contiguous per instruction.
  #pragma unroll
  for (int j = 0; j < 4; ++j) {
    int idx = j*256 + tid;
    int c = idx >> 4, q = idx & 15;
    float a0=0.f, a1=0.f, a2=0.f, a3=0.f;
    #pragma unroll
    for (int s = 0; s < KS; ++s) {
      uint2 v = *(const uint2*)&part[(base+s)*4096 + (size_t)c*64 + q*4];
      a0 += bu2f((ushort)(v.x & 0xffff)); a1 += bu2f((ushort)(v.x >> 16));
      a2 += bu2f((ushort)(v.y & 0xffff)); a3 += bu2f((ushort)(v.y >> 16));
    }
    int nl = q*4;
    size_t gidx = (size_t)(b*CH + c)*NN + tile*64 + nl;
    float4 xv = *(const float4*)&x[gidx];
    float bc = ob[c];
    float4 o;
    o.x = a0*linv[nl+0] + bc + xv.x;
    o.y = a1*linv[nl+1] + bc + xv.y;
    o.z = a2*linv[nl+2] + bc + xv.z;
    o.w = a3*linv[nl+3] + bc + xv.w;
    *(float4*)&out[gidx] = o;
  }
}

extern "C" void kernel_launch(void* const* d_in, const int* in_sizes, int n_in,
                              void* d_out, int out_size, void* d_ws, size_t ws_size,
                              hipStream_t stream) {
  const float* x    = (const float*)d_in[0];
  const float* q1w  = (const float*)d_in[1];
  const float* q1g  = (const float*)d_in[2];
  const float* q1b  = (const float*)d_in[3];
  const float* q2w  = (const float*)d_in[4];
  const float* q2g  = (const float*)d_in[5];
  const float* q2b  = (const float*)d_in[6];
  const float* q3w  = (const float*)d_in[7];
  const float* q3g  = (const float*)d_in[8];
  const float* q3b  = (const float*)d_in[9];
  const float* khw  = (const float*)d_in[10];
  const float* khb  = (const float*)d_in[11];
  const float* klw  = (const float*)d_in[12];
  const float* klb  = (const float*)d_in[13];
  const float* kfw  = (const float*)d_in[14];
  const float* kfb  = (const float*)d_in[15];
  const float* vbg  = (const float*)d_in[16];
  const float* vbb  = (const float*)d_in[17];
  const float* vw   = (const float*)d_in[18];
  const float* vb   = (const float*)d_in[19];
  const float* outw = (const float*)d_in[20];
  const float* outb = (const float*)d_in[21];

  char*   wsb  = (char*)d_ws;
  float*  biasf= (float*)(wsb + OFF_BIAS);
  bf16*   wh   = (bf16*)(wsb + OFF_WH_B);
  bf16*   lowg = (bf16*)(wsb + OFF_LOW_B);
  bf16*   qgT  = (bf16*)(wsb + OFF_Q_B);
  bf16*   kgT  = (bf16*)(wsb + OFF_K_B);
  bf16*   vgc  = (bf16*)(wsb + OFF_V_B);
  ushort* part = (ushort*)(wsb + OFF_P_B);
  float*  pml  = (float*)(wsb + OFF_ML_B);

  hipLaunchKernelGGL(setup_fold, dim3(16), dim3(256), 0, stream,
                     q1w,q1g,q1b,q2w,q2g,q2b,q3w,q3g,q3b,
                     khw,khb,klw,klb,kfw,kfb,vbg,vbb,vw,vb,outw, biasf, wh);
  hipLaunchKernelGGL(pool_low, dim3(BATCH*CH*NN/1024), dim3(256), 0, stream, x, lowg);
  hipLaunchKernelGGL(qkv_kernel, dim3(BATCH*NT*2), dim3(256), 0, stream,
                     x, biasf, wh, lowg, qgT, kgT, vgc);
  hipLaunchKernelGGL(attn_partial, dim3(BATCH*NT*KS), dim3(256), 0, stream,
                     qgT, kgT, vgc, part, pml);
  hipLaunchKernelGGL(attn_reduce, dim3(BATCH*NT), dim3(256), 0, stream,
                     part, pml, x, outb, (float*)d_out);
}